// Round 4
// baseline (218.089 us; speedup 1.0000x reference)
//
#include <hip/hip_runtime.h>
#include <hip/hip_bf16.h>
#include <stdint.h>

#define Bn 8
#define Sn 4096
#define Hn 768
#define Dn 1024
#define Wn 2048

typedef __attribute__((ext_vector_type(8))) short short8;
typedef __attribute__((ext_vector_type(4))) short short4v;
typedef __attribute__((ext_vector_type(4))) float floatx4;

__device__ __forceinline__ void load_lds16(const void* g, void* l) {
  __builtin_amdgcn_global_load_lds(
      (const __attribute__((address_space(1))) void*)g,
      (__attribute__((address_space(3))) void*)l, 16, 0, 0);
}

// -------- kernel 1: fused prep --------------------------------------------------
// blocks [0, 768): transpose proj_w (H x D fp32) -> B^T (D x H bf16), 32x32 tiles
// blocks [768, 896): boundary table starts[b][w] from sorted word_ids
__global__ __launch_bounds__(256) void k_prep(const float* __restrict__ pw,
                                              const int* __restrict__ wid,
                                              __hip_bfloat16* __restrict__ wb,
                                              int* __restrict__ starts) {
  if (blockIdx.x < 768) {
    __shared__ float tile[32][33];
    const int bt = blockIdx.x;            // 32 x 24 tile grid
    const int d0 = (bt % 32) * 32, h0 = (bt / 32) * 32;
    const int tx = threadIdx.x & 31, ty = threadIdx.x >> 5;  // 32 x 8
#pragma unroll
    for (int i = 0; i < 32; i += 8)
      tile[ty + i][tx] = pw[(size_t)(h0 + ty + i) * Dn + d0 + tx];
    __syncthreads();
#pragma unroll
    for (int i = 0; i < 32; i += 8)
      wb[(size_t)(d0 + ty + i) * Hn + h0 + tx] = (__hip_bfloat16)tile[tx][ty + i];
  } else {
    const int bid = blockIdx.x - 768;       // 128 blocks cover (Bn, Sn)
    const int g = bid * 256 + threadIdx.x;  // 0 .. 32767
    const int b = g >> 12, s = g & (Sn - 1);
    const int* wbi = wid + (size_t)b * Sn;
    int* sb = starts + b * (Wn + 1);
    const int cur = wbi[s];
    const int prev = (s == 0) ? -1 : wbi[s - 1];
    for (int ww = prev + 1; ww <= cur; ++ww) sb[ww] = s;
    if (s == Sn - 1)
      for (int ww = cur + 1; ww <= Wn; ++ww) sb[ww] = Sn;
  }
}

// ------------- kernel 2: segment mean + validity mask ---------------------------
// One block per 32 contiguous words. Boundaries loaded once into LDS (kills the
// per-word dependent-load prologue); emb rows then stream in sorted order, so
// the global read pattern is fully sequential. 512 blocks = 2/CU.
__global__ __launch_bounds__(256) void k_words(const float* __restrict__ emb,
                                               const int* __restrict__ masks,
                                               const int* __restrict__ starts,
                                               __hip_bfloat16* __restrict__ wa,
                                               float* __restrict__ out_masks) {
  __shared__ int s_bnd[33];
  __shared__ float s_inv[32];

  const int b = blockIdx.y;
  const int W0 = blockIdx.x * 32;
  const int t = threadIdx.x;
  const int wave = t >> 6, lane = t & 63;

  const int* sb = starts + b * (Wn + 1);
  if (t < 33) s_bnd[t] = sb[W0 + t];
  __syncthreads();

  if (t < 32) {
    const int start = s_bnd[t], end = s_bnd[t + 1];
    const int count = end - start;
    const int* mb = masks + (size_t)b * Sn;
    int mcount = 0;
    for (int s = start; s < end; ++s) mcount += mb[s];  // L2-hot, parallel over 32 thr
    const bool valid = (count > 0) && (count == mcount);
    s_inv[t] = valid ? 1.0f / (float)count : 0.0f;
    out_masks[(size_t)b * Wn + W0 + t] = valid ? 1.0f : 0.0f;
  }
  __syncthreads();

  const float* eb = emb + (size_t)b * Sn * Hn;
  for (int widx = wave; widx < 32; widx += 4) {
    const int start = s_bnd[widx], end = s_bnd[widx + 1];
    const float inv = s_inv[widx];

    floatx4 sum[3] = {{0.f, 0.f, 0.f, 0.f}, {0.f, 0.f, 0.f, 0.f}, {0.f, 0.f, 0.f, 0.f}};
    int s = start;
    for (; s + 1 < end; s += 2) {
      const floatx4* r0 = (const floatx4*)(eb + (size_t)s * Hn);
      const floatx4* r1 = (const floatx4*)(eb + (size_t)(s + 1) * Hn);
#pragma unroll
      for (int j = 0; j < 3; ++j) sum[j] += r0[j * 64 + lane];
#pragma unroll
      for (int j = 0; j < 3; ++j) sum[j] += r1[j * 64 + lane];
    }
    if (s < end) {
      const floatx4* r0 = (const floatx4*)(eb + (size_t)s * Hn);
#pragma unroll
      for (int j = 0; j < 3; ++j) sum[j] += r0[j * 64 + lane];
    }

    const size_t rowbase = ((size_t)b * Wn + W0 + widx) * Hn;
#pragma unroll
    for (int j = 0; j < 3; ++j) {
      short4v o;
#pragma unroll
      for (int c = 0; c < 4; ++c) {
        __hip_bfloat16 h = (__hip_bfloat16)(sum[j][c] * inv);
        o[c] = *reinterpret_cast<short*>(&h);
      }
      *(short4v*)&wa[rowbase + (size_t)(j * 64 + lane) * 4] = o;
    }
  }
}

// ------------- kernel 3: bf16 MFMA GEMM  C = A @ B + bias -----------------------
// A: (M=16384, K=768) bf16, Bt: (N=1024, K=768) bf16, C: fp32.
// 128x128 block tile, BK=32, 4 waves each 64x64 (4x4 of 16x16x32 MFMA).
// XCD-aware swizzle: each XCD owns a strip of 16 m-tiles x all 8 n-tiles
// (n fastest) so A-tiles stay L2-resident per XCD.
__global__ __launch_bounds__(256) void k_gemm(const short* __restrict__ A,
                                              const short* __restrict__ Bt,
                                              const float* __restrict__ bias,
                                              float* __restrict__ out) {
  constexpr int K = Hn;   // 768
  constexpr int N = Dn;   // 1024
  __shared__ __align__(16) short lsA[128 * 32];
  __shared__ __align__(16) short lsB[128 * 32];

  const int t = threadIdx.x;
  const int lane = t & 63, wave = t >> 6;
  const int wm = wave >> 1, wn = wave & 1;
  const int lane16 = lane & 15, quad = lane >> 4;

  const int linear = blockIdx.x;          // 1024 blocks
  const int xcd = linear & 7;
  const int o = linear >> 3;              // per-XCD ordinal, 0..127
  const int m0 = (xcd * 16 + (o >> 3)) * 128;
  const int n0 = (o & 7) * 128;

  const int lrow = t >> 2;
  const int lcol = (t & 3) * 8;
  const short* gA0 = A + (size_t)(m0 + lrow) * K + lcol;
  const short* gB0 = Bt + (size_t)(n0 + lrow) * K + lcol;
  short* lA0 = &lsA[lrow * 32 + lcol];
  short* lB0 = &lsB[lrow * 32 + lcol];

  floatx4 acc[4][4];
#pragma unroll
  for (int i = 0; i < 4; ++i)
#pragma unroll
    for (int j = 0; j < 4; ++j) acc[i][j] = (floatx4){0.f, 0.f, 0.f, 0.f};

  for (int k0 = 0; k0 < K; k0 += 32) {
    load_lds16(gA0 + k0, lA0);
    load_lds16(gA0 + (size_t)64 * K + k0, lA0 + 64 * 32);
    load_lds16(gB0 + k0, lB0);
    load_lds16(gB0 + (size_t)64 * K + k0, lB0 + 64 * 32);
    __syncthreads();

    short8 af[4], bf[4];
#pragma unroll
    for (int mi = 0; mi < 4; ++mi)
      af[mi] = *(const short8*)&lsA[(wm * 64 + mi * 16 + lane16) * 32 + quad * 8];
#pragma unroll
    for (int ni = 0; ni < 4; ++ni)
      bf[ni] = *(const short8*)&lsB[(wn * 64 + ni * 16 + lane16) * 32 + quad * 8];

#pragma unroll
    for (int mi = 0; mi < 4; ++mi)
#pragma unroll
      for (int ni = 0; ni < 4; ++ni)
        acc[mi][ni] = __builtin_amdgcn_mfma_f32_16x16x32_bf16(af[mi], bf[ni], acc[mi][ni], 0, 0, 0);
    __syncthreads();
  }

  // epilogue: C/D layout col = lane&15, row = quad*4 + r  (m89/m91-verified)
#pragma unroll
  for (int mi = 0; mi < 4; ++mi) {
#pragma unroll
    for (int ni = 0; ni < 4; ++ni) {
      const int n = n0 + wn * 64 + ni * 16 + lane16;
      const float bv = bias[n];
#pragma unroll
      for (int r = 0; r < 4; ++r) {
        const int m = m0 + wm * 64 + mi * 16 + quad * 4 + r;
        out[(size_t)m * N + n] = acc[mi][ni][r] + bv;
      }
    }
  }
}

extern "C" void kernel_launch(void* const* d_in, const int* in_sizes, int n_in,
                              void* d_out, int out_size, void* d_ws, size_t ws_size,
                              hipStream_t stream) {
  const float* emb    = (const float*)d_in[0];  // (8, 4096, 768)
  const float* proj_w = (const float*)d_in[1];  // (768, 1024)
  const float* proj_b = (const float*)d_in[2];  // (1024,)
  const int*   masks  = (const int*)d_in[3];    // (8, 4096)
  const int*   wid    = (const int*)d_in[4];    // (8, 4096)

  float* out = (float*)d_out;                       // (8, 2048, 1024) fp32
  float* out_masks = out + (size_t)Bn * Wn * Dn;    // (8, 2048) as 0.0/1.0

  __hip_bfloat16* wb = (__hip_bfloat16*)d_ws;            // B^T: (1024, 768) bf16
  __hip_bfloat16* wa = wb + (size_t)Dn * Hn;             // A:   (16384, 768) bf16
  int* starts = (int*)(wa + (size_t)Bn * Wn * Hn);       // (8, 2049) boundaries

  // 1. fused: transpose proj_w + boundary table
  k_prep<<<dim3(768 + (Bn * Sn) / 256), 256, 0, stream>>>(proj_w, wid, wb, starts);

  // 2. segment means + masks (one block per 32 contiguous words)
  k_words<<<dim3(Wn / 32, Bn), 256, 0, stream>>>(emb, masks, starts, wa, out_masks);

  // 3. projection GEMM + bias (XCD-swizzled 1-D grid)
  k_gemm<<<dim3(1024), 256, 0, stream>>>((const short*)wa, (const short*)wb, proj_b, out);
}

// Round 5
// 208.004 us; speedup vs baseline: 1.0485x; 1.0485x over previous
//
#include <hip/hip_runtime.h>
#include <hip/hip_bf16.h>
#include <stdint.h>

#define Bn 8
#define Sn 4096
#define Hn 768
#define Dn 1024
#define Wn 2048

typedef __attribute__((ext_vector_type(8))) short short8;
typedef __attribute__((ext_vector_type(4))) short short4v;
typedef __attribute__((ext_vector_type(4))) float floatx4;

__device__ __forceinline__ void load_lds16(const void* g, void* l) {
  __builtin_amdgcn_global_load_lds(
      (const __attribute__((address_space(1))) void*)g,
      (__attribute__((address_space(3))) void*)l, 16, 0, 0);
}

// -------- kernel 1: fused prep --------------------------------------------------
// blocks [0, 768): transpose proj_w (H x D fp32) -> B^T (D x H bf16), 32x32 tiles
// blocks [768, 896): boundary table starts[b][w] from sorted word_ids
__global__ __launch_bounds__(256) void k_prep(const float* __restrict__ pw,
                                              const int* __restrict__ wid,
                                              __hip_bfloat16* __restrict__ wb,
                                              int* __restrict__ starts) {
  if (blockIdx.x < 768) {
    __shared__ float tile[32][33];
    const int bt = blockIdx.x;            // 32 x 24 tile grid
    const int d0 = (bt % 32) * 32, h0 = (bt / 32) * 32;
    const int tx = threadIdx.x & 31, ty = threadIdx.x >> 5;  // 32 x 8
#pragma unroll
    for (int i = 0; i < 32; i += 8)
      tile[ty + i][tx] = pw[(size_t)(h0 + ty + i) * Dn + d0 + tx];
    __syncthreads();
#pragma unroll
    for (int i = 0; i < 32; i += 8)
      wb[(size_t)(d0 + ty + i) * Hn + h0 + tx] = (__hip_bfloat16)tile[tx][ty + i];
  } else {
    const int bid = blockIdx.x - 768;       // 128 blocks cover (Bn, Sn)
    const int g = bid * 256 + threadIdx.x;  // 0 .. 32767
    const int b = g >> 12, s = g & (Sn - 1);
    const int* wbi = wid + (size_t)b * Sn;
    int* sb = starts + b * (Wn + 1);
    const int cur = wbi[s];
    const int prev = (s == 0) ? -1 : wbi[s - 1];
    for (int ww = prev + 1; ww <= cur; ++ww) sb[ww] = s;
    if (s == Sn - 1)
      for (int ww = cur + 1; ww <= Wn; ++ww) sb[ww] = Sn;
  }
}

// ------------- kernel 2: segment mean + validity mask ---------------------------
// One wave per word (4 words per 256-thread block). 4096 blocks -> 8 blocks/CU,
// 32 waves/CU in flight: this grid size IS the latency hiding (R4's 512-block
// variant regressed 4x on outstanding loads — do not shrink the grid).
__global__ __launch_bounds__(256) void k_words(const float* __restrict__ emb,
                                               const int* __restrict__ masks,
                                               const int* __restrict__ starts,
                                               __hip_bfloat16* __restrict__ wa,
                                               float* __restrict__ out_masks) {
  const int b = blockIdx.y;
  const int wave = threadIdx.x >> 6, lane = threadIdx.x & 63;
  const int w = blockIdx.x * 4 + wave;

  const int* sb = starts + b * (Wn + 1);
  const int start = sb[w];
  const int end = sb[w + 1];
  const int count = end - start;

  // parallel all-ones mask check (one 64-lane load per 64 subwords)
  const int* mb = masks + (size_t)b * Sn;
  bool allone = true;
  for (int s0 = start; s0 < end; s0 += 64) {
    const int idx = s0 + lane;
    allone = allone && ((idx < end) ? (mb[idx] == 1) : true);
  }
  const bool valid = (count > 0) && __all(allone);
  const float inv = valid ? 1.0f / (float)count : 0.0f;

  floatx4 sum[3] = {{0.f, 0.f, 0.f, 0.f}, {0.f, 0.f, 0.f, 0.f}, {0.f, 0.f, 0.f, 0.f}};
  const float* eb = emb + (size_t)b * Sn * Hn;
  int s = start;
  for (; s + 1 < end; s += 2) {
    const floatx4* r0 = (const floatx4*)(eb + (size_t)s * Hn);
    const floatx4* r1 = (const floatx4*)(eb + (size_t)(s + 1) * Hn);
#pragma unroll
    for (int j = 0; j < 3; ++j) sum[j] += r0[j * 64 + lane];
#pragma unroll
    for (int j = 0; j < 3; ++j) sum[j] += r1[j * 64 + lane];
  }
  if (s < end) {
    const floatx4* r0 = (const floatx4*)(eb + (size_t)s * Hn);
#pragma unroll
    for (int j = 0; j < 3; ++j) sum[j] += r0[j * 64 + lane];
  }

  const size_t rowbase = ((size_t)b * Wn + w) * Hn;
#pragma unroll
  for (int j = 0; j < 3; ++j) {
    short4v o;
#pragma unroll
    for (int c = 0; c < 4; ++c) {
      __hip_bfloat16 h = (__hip_bfloat16)(sum[j][c] * inv);
      o[c] = *reinterpret_cast<short*>(&h);
    }
    *(short4v*)&wa[rowbase + (size_t)(j * 64 + lane) * 4] = o;
  }
  if (lane == 0) out_masks[(size_t)b * Wn + w] = valid ? 1.0f : 0.0f;
}

// ------------- kernel 3: bf16 MFMA GEMM  C = A @ B + bias -----------------------
// A: (M=16384, K=768) bf16, Bt: (N=1024, K=768) bf16, C: fp32.
// 128x128 block tile, BK=64 as TWO concatenated BK=32 panels (identical
// per-panel layout to the validated m97 structure -> keeps global_load_lds
// lane-contiguity and fragment-read pattern), 32 MFMA per barrier interval,
// 12 barriers instead of 24. XCD-aware swizzle: each XCD owns a strip of
// 16 m-tiles x all 8 n-tiles (n fastest) so A-tiles stay L2-resident per XCD.
__global__ __launch_bounds__(256) void k_gemm(const short* __restrict__ A,
                                              const short* __restrict__ Bt,
                                              const float* __restrict__ bias,
                                              float* __restrict__ out) {
  constexpr int K = Hn;   // 768
  constexpr int N = Dn;   // 1024
  __shared__ __align__(16) short lsA[2][128 * 32];
  __shared__ __align__(16) short lsB[2][128 * 32];

  const int t = threadIdx.x;
  const int lane = t & 63, wave = t >> 6;
  const int wm = wave >> 1, wn = wave & 1;
  const int lane16 = lane & 15, quad = lane >> 4;

  const int linear = blockIdx.x;          // 1024 blocks
  const int xcd = linear & 7;
  const int o = linear >> 3;              // per-XCD ordinal, 0..127
  const int m0 = (xcd * 16 + (o >> 3)) * 128;
  const int n0 = (o & 7) * 128;

  const int lrow = t >> 2;
  const int lcol = (t & 3) * 8;
  const short* gA0 = A + (size_t)(m0 + lrow) * K + lcol;
  const short* gB0 = Bt + (size_t)(n0 + lrow) * K + lcol;
  const int loff = lrow * 32 + lcol;

  // bias hoisted out of the K-loop
  float bv[4];
#pragma unroll
  for (int ni = 0; ni < 4; ++ni)
    bv[ni] = bias[n0 + wn * 64 + ni * 16 + lane16];

  floatx4 acc[4][4];
#pragma unroll
  for (int i = 0; i < 4; ++i)
#pragma unroll
    for (int j = 0; j < 4; ++j) acc[i][j] = (floatx4){0.f, 0.f, 0.f, 0.f};

  for (int k0 = 0; k0 < K; k0 += 64) {
    // panel 0: k0..k0+31, panel 1: k0+32..k0+63
    load_lds16(gA0 + k0,                    &lsA[0][loff]);
    load_lds16(gA0 + (size_t)64 * K + k0,   &lsA[0][loff + 64 * 32]);
    load_lds16(gA0 + k0 + 32,               &lsA[1][loff]);
    load_lds16(gA0 + (size_t)64 * K + k0 + 32, &lsA[1][loff + 64 * 32]);
    load_lds16(gB0 + k0,                    &lsB[0][loff]);
    load_lds16(gB0 + (size_t)64 * K + k0,   &lsB[0][loff + 64 * 32]);
    load_lds16(gB0 + k0 + 32,               &lsB[1][loff]);
    load_lds16(gB0 + (size_t)64 * K + k0 + 32, &lsB[1][loff + 64 * 32]);
    __syncthreads();

#pragma unroll
    for (int sp = 0; sp < 2; ++sp) {
      short8 af[4], bf[4];
#pragma unroll
      for (int mi = 0; mi < 4; ++mi)
        af[mi] = *(const short8*)&lsA[sp][(wm * 64 + mi * 16 + lane16) * 32 + quad * 8];
#pragma unroll
      for (int ni = 0; ni < 4; ++ni)
        bf[ni] = *(const short8*)&lsB[sp][(wn * 64 + ni * 16 + lane16) * 32 + quad * 8];

#pragma unroll
      for (int mi = 0; mi < 4; ++mi)
#pragma unroll
        for (int ni = 0; ni < 4; ++ni)
          acc[mi][ni] = __builtin_amdgcn_mfma_f32_16x16x32_bf16(af[mi], bf[ni], acc[mi][ni], 0, 0, 0);
    }
    __syncthreads();
  }

  // epilogue: C/D layout col = lane&15, row = quad*4 + r  (m89/m91-verified)
#pragma unroll
  for (int mi = 0; mi < 4; ++mi) {
#pragma unroll
    for (int ni = 0; ni < 4; ++ni) {
      const int n = n0 + wn * 64 + ni * 16 + lane16;
#pragma unroll
      for (int r = 0; r < 4; ++r) {
        const int m = m0 + wm * 64 + mi * 16 + quad * 4 + r;
        out[(size_t)m * N + n] = acc[mi][ni][r] + bv[ni];
      }
    }
  }
}

extern "C" void kernel_launch(void* const* d_in, const int* in_sizes, int n_in,
                              void* d_out, int out_size, void* d_ws, size_t ws_size,
                              hipStream_t stream) {
  const float* emb    = (const float*)d_in[0];  // (8, 4096, 768)
  const float* proj_w = (const float*)d_in[1];  // (768, 1024)
  const float* proj_b = (const float*)d_in[2];  // (1024,)
  const int*   masks  = (const int*)d_in[3];    // (8, 4096)
  const int*   wid    = (const int*)d_in[4];    // (8, 4096)

  float* out = (float*)d_out;                       // (8, 2048, 1024) fp32
  float* out_masks = out + (size_t)Bn * Wn * Dn;    // (8, 2048) as 0.0/1.0

  __hip_bfloat16* wb = (__hip_bfloat16*)d_ws;            // B^T: (1024, 768) bf16
  __hip_bfloat16* wa = wb + (size_t)Dn * Hn;             // A:   (16384, 768) bf16
  int* starts = (int*)(wa + (size_t)Bn * Wn * Hn);       // (8, 2049) boundaries

  // 1. fused: transpose proj_w + boundary table
  k_prep<<<dim3(768 + (Bn * Sn) / 256), 256, 0, stream>>>(proj_w, wid, wb, starts);

  // 2. segment means + masks (one wave per word)
  k_words<<<dim3(Wn / 4, Bn), 256, 0, stream>>>(emb, masks, starts, wa, out_masks);

  // 3. projection GEMM + bias (XCD-swizzled 1-D grid, BK=64 two-panel)
  k_gemm<<<dim3(1024), 256, 0, stream>>>((const short*)wa, (const short*)wb, proj_b, out);
}